// Round 8
// baseline (124.609 us; speedup 1.0000x reference)
//
#include <hip/hip_runtime.h>

// Problem constants (B=4, N=2048, DIM=1024, HEAD=16, HD=64)
#define B_    4
#define N_    2048
#define DIM_  1024
#define HEAD_ 16
#define HD_   64
#define M_    (B_*N_)    // 8192 rows
#define E_    (2*DIM_)   // 2048 projection outputs

typedef short          frag8 __attribute__((ext_vector_type(8)));  // 8 bf16 (4 VGPRs)
typedef float          facc4 __attribute__((ext_vector_type(4)));  // MFMA accum
typedef unsigned short ush4  __attribute__((ext_vector_type(4)));
typedef _Float16       hv4   __attribute__((ext_vector_type(4)));  // 4 f16 (2 VGPRs)
typedef _Float16       hv2   __attribute__((ext_vector_type(2)));

#define AS1 __attribute__((address_space(1)))
#define AS3 __attribute__((address_space(3)))

__device__ __forceinline__ void gld_lds16(const void* g, void* l) {
    // async global->LDS, 16B per lane; LDS dest = wave-uniform base + lane*16
    __builtin_amdgcn_global_load_lds((AS1 void*)(void*)g, (AS3 void*)l, 16, 0, 0);
}

__device__ __forceinline__ unsigned short f2bf(float f) {
    return __builtin_bit_cast(unsigned short, (__bf16)f);
}

// ---------------- Kernel 1: LayerNorm -> bf16 ----------------
__global__ __launch_bounds__(256) void ln_kernel(const float* __restrict__ x,
                                                 const float* __restrict__ lw,
                                                 const float* __restrict__ lb,
                                                 unsigned short* __restrict__ xn) {
    const int row = blockIdx.x;          // 0..8191
    const int t   = threadIdx.x;         // 256 threads, 4 elems each
    const float4 v = ((const float4*)(x + (size_t)row * DIM_))[t];
    float s  = v.x + v.y + v.z + v.w;
    float sq = v.x*v.x + v.y*v.y + v.z*v.z + v.w*v.w;
#pragma unroll
    for (int off = 32; off > 0; off >>= 1) {
        s  += __shfl_xor(s,  off);
        sq += __shfl_xor(sq, off);
    }
    __shared__ float red[8];
    const int w = t >> 6;
    if ((t & 63) == 0) { red[w] = s; red[4 + w] = sq; }
    __syncthreads();
    s  = red[0] + red[1] + red[2] + red[3];
    sq = red[4] + red[5] + red[6] + red[7];
    const float mu   = s * (1.0f / DIM_);
    const float rstd = rsqrtf(sq * (1.0f / DIM_) - mu * mu + 1e-5f);
    const float4 wv4 = ((const float4*)lw)[t];
    const float4 bv4 = ((const float4*)lb)[t];
    ush4 o;
    o[0] = f2bf((v.x - mu) * rstd * wv4.x + bv4.x);
    o[1] = f2bf((v.y - mu) * rstd * wv4.y + bv4.y);
    o[2] = f2bf((v.z - mu) * rstd * wv4.z + bv4.z);
    o[3] = f2bf((v.w - mu) * rstd * wv4.w + bv4.w);
    *(ush4*)(xn + (size_t)row * DIM_ + t * 4) = o;
}

// ---------------- Kernel 1b: Wqk f32 -> bf16 ----------------
__global__ __launch_bounds__(256) void cvt_kernel(const float* __restrict__ in,
                                                  unsigned short* __restrict__ outp) {
    const int i = blockIdx.x * 256 + threadIdx.x;   // 524288 float4 groups
    const float4 v = ((const float4*)in)[i];
    ush4 o;
    o[0] = f2bf(v.x); o[1] = f2bf(v.y); o[2] = f2bf(v.z); o[3] = f2bf(v.w);
    ((ush4*)outp)[i] = o;
}

// ---------------- Kernel 1c: v16[bh][n] = (f16)(A[b][n][h] * wv) ------------
__global__ __launch_bounds__(256) void vprep_kernel(const float* __restrict__ A,
                                                    const float* __restrict__ wv,
                                                    unsigned short* __restrict__ v16) {
    const int bh = blockIdx.x;           // 0..63
    const int b = bh >> 4, h = bh & 15;
    const float wvv = wv[0];
#pragma unroll
    for (int i = 0; i < 8; ++i) {
        const int n = i * 256 + threadIdx.x;
        const float f = A[((size_t)(b * N_ + n)) * HEAD_ + h] * wvv;
        v16[(size_t)bh * N_ + n] = __builtin_bit_cast(unsigned short, (_Float16)f);
    }
}

// ---------------- Kernel 2: qk = xn @ Wqk^T  (NT GEMM, bf16 MFMA) ----------------
// 128x128 tile, BK=64, 4 waves of 64x64. Both-sides XOR swizzle (verified).
// XCD-aware block swizzle (T1): nwg=1024 (%8==0) -> each XCD owns 128
// consecutive tiles = 2 bn-panels (512 KB of wb, L2-resident).
// Scale folded into q: 1/32 (dim^-0.5) * log2(e)  -> attn uses exp2 directly.
__global__ __launch_bounds__(256) void gemm_qk(const unsigned short* __restrict__ xn,
                                               const unsigned short* __restrict__ wb,
                                               unsigned short* __restrict__ qo,
                                               unsigned short* __restrict__ ko) {
    __shared__ __attribute__((aligned(16))) unsigned short As[128 * 64];
    __shared__ __attribute__((aligned(16))) unsigned short Bs[128 * 64];
    const int t    = threadIdx.x;
    const int lane = t & 63;
    const int w    = t >> 6;
    const int wr   = w & 1, wc = w >> 1;        // 2x2 wave grid, 64x64 each
    const int lr   = lane & 15, lg = lane >> 4; // frag row-lane / k-group
    const int bid  = blockIdx.x;
    const int swz  = (bid & 7) * 128 + (bid >> 3);   // bijective XCD swizzle
    const int bm   = swz & 63, bn = swz >> 6;
    const int m0   = bm * 128, e0 = bn * 128;

    facc4 acc[4][4] = {};

    for (int k0 = 0; k0 < DIM_; k0 += 64) {
#pragma unroll
        for (int it = 0; it < 4; ++it) {
            const int seg = it * 256 + t;
            const int row = seg >> 3;
            const int ss  = (seg & 7) ^ (row & 7);         // pre-swizzled source
            unsigned short* dstA = (unsigned short*)As + (size_t)(it * 256 + (t & ~63)) * 8;
            unsigned short* dstB = (unsigned short*)Bs + (size_t)(it * 256 + (t & ~63)) * 8;
            gld_lds16(xn + (size_t)(m0 + row) * DIM_ + k0 + ss * 8, dstA);
            gld_lds16(wb + (size_t)(e0 + row) * DIM_ + k0 + ss * 8, dstB);
        }
        __syncthreads();

        frag8 af[4][2];
#pragma unroll
        for (int rt = 0; rt < 4; ++rt) {
            const int row = wr * 64 + rt * 16 + lr;
            const int sw  = (row & 7) << 4;
            af[rt][0] = *(const frag8*)((const char*)As + row * 128 + ((lg * 16) ^ sw));
            af[rt][1] = *(const frag8*)((const char*)As + row * 128 + ((64 + lg * 16) ^ sw));
        }
#pragma unroll
        for (int ct = 0; ct < 4; ++ct) {
            const int row = wc * 64 + ct * 16 + lr;
            const int sw  = (row & 7) << 4;
            const frag8 b0 = *(const frag8*)((const char*)Bs + row * 128 + ((lg * 16) ^ sw));
            const frag8 b1 = *(const frag8*)((const char*)Bs + row * 128 + ((64 + lg * 16) ^ sw));
#pragma unroll
            for (int rt = 0; rt < 4; ++rt) {
                acc[rt][ct] = __builtin_amdgcn_mfma_f32_16x16x32_bf16(af[rt][0], b0, acc[rt][ct], 0, 0, 0);
                acc[rt][ct] = __builtin_amdgcn_mfma_f32_16x16x32_bf16(af[rt][1], b1, acc[rt][ct], 0, 0, 0);
            }
        }
        __syncthreads();
    }

    // Epilogue: scatter to head-major q/k [bh][n][64]; fold scale*log2e into q.
    const float QSCALE = 0.03125f * 1.4426950408889634f;
#pragma unroll
    for (int rt = 0; rt < 4; ++rt) {
#pragma unroll
        for (int ct = 0; ct < 4; ++ct) {
            const int eg = e0 + wc * 64 + ct * 16 + lr;
#pragma unroll
            for (int r = 0; r < 4; ++r) {
                const int   mg = m0 + wr * 64 + rt * 16 + lg * 4 + r;  // C/D: row=(lane>>4)*4+reg
                const int   b  = mg >> 11;
                const int   n  = mg & (N_ - 1);
                const float val = acc[rt][ct][r];
                if (eg < DIM_) {
                    const int h = eg >> 6, d = eg & 63;
                    qo[((size_t)((b * HEAD_ + h) * N_ + n)) * HD_ + d] = f2bf(val * QSCALE);
                } else {
                    const int e2 = eg - DIM_;
                    const int h = e2 >> 6, d = e2 & 63;
                    ko[((size_t)((b * HEAD_ + h) * N_ + n)) * HD_ + d] = f2bf(val);
                }
            }
        }
    }
}

// ---------------- Kernel 3: attention partials (split-KV x4) ----------------
// 3-buffer counted-vmcnt pipeline (T3/T4): prologue stages chunks 0,1; each
// iter: s_waitcnt vmcnt(2) [own chunk-c loads landed, c+1 in flight] BEFORE
// raw s_barrier [so post-barrier, ALL waves' chunk-c quarters are visible],
// then stage c+2, then compute c. Never drains vmcnt to 0 mid-loop (the
// __syncthreads full-drain was the r7 stall). Buffer safety: stage(c+2)
// writes buf[(c+2)%3] = buf[(c-1)%3], whose last reader (CHUNK(c-1)) is
// separated by this iter's barrier.
__global__ __launch_bounds__(256) void attn_kernel(const unsigned short* __restrict__ q,
                                                   const unsigned short* __restrict__ kmat,
                                                   const unsigned short* __restrict__ v16,
                                                   float2* __restrict__ part) {
    __shared__ __attribute__((aligned(16))) char KsB[3 * 8192];
    const int t    = threadIdx.x;
    const int lane = t & 63, w = t >> 6;        // 4 waves, 64 q-rows each
    const int lr   = lane & 15, lg = lane >> 4;
    const int id    = blockIdx.x;
    const int split = id >> 9;                  // 0..3 (KV quarter)
    const int bh    = (id >> 3) & 63;
    const int qblk  = id & 7;
    const int b     = bh >> 4, h = bh & 15;
    const int q0    = qblk * 256 + w * 64;

    // per-lane constants
    const int row0  = t >> 3;
    const int koff  = row0 * HD_ + (((t & 7) ^ (row0 & 7)) * 8);   // staging src (elems)
    const int wbase = (t & ~63) * 16;                              // staging LDS dst (bytes)
    const int sw    = (lr & 7) << 4;
    const int off_h0 = lr * 128 + ((lg * 16) ^ sw);                // ds_read vaddr (bytes)
    const int off_h1 = lr * 128 + ((64 + lg * 16) ^ sw);

    const unsigned short* qbase = q    + (size_t)bh * N_ * HD_;
    const unsigned short* kfix  = kmat + (size_t)bh * N_ * HD_ + (size_t)split * 512 * HD_;
    const unsigned short* vfix  = v16  + (size_t)bh * N_ + split * 512;

    // Q fragments in registers (B-operand: col=lr -> q-row, k = hh*32 + lg*8)
    frag8 qf[4][2];
#pragma unroll
    for (int qt = 0; qt < 4; ++qt) {
#pragma unroll
        for (int hh = 0; hh < 2; ++hh)
            qf[qt][hh] = *(const frag8*)(qbase + (size_t)(q0 + qt * 16 + lr) * HD_ + hh * 32 + lg * 8);
    }

    // PV A-operand masks: row0 -> v (num), row1 -> 1 (den)
    hv4 sel, one1;
#pragma unroll
    for (int j = 0; j < 4; ++j) {
        sel[j]  = (lr == 0) ? (_Float16)1.f : (_Float16)0.f;
        one1[j] = (lr == 1) ? (_Float16)1.f : (_Float16)0.f;
    }
    const facc4 z4 = {0.f, 0.f, 0.f, 0.f};
    facc4 acc[4] = {};

#define STAGE(c) do {                                                          \
        gld_lds16(kfix + (c) * 64 * HD_ + koff,                                \
                  KsB + ((c) % 3) * 8192 + wbase);                             \
        gld_lds16(kfix + (c) * 64 * HD_ + koff + 2048,                         \
                  KsB + ((c) % 3) * 8192 + 4096 + wbase);                      \
    } while (0)

#define CHUNK(c) do {                                                          \
        _Pragma("unroll")                                                      \
        for (int ct = 0; ct < 4; ++ct) {                                       \
            const frag8 kf0 = *(const frag8*)(KsB + ((c) % 3) * 8192 + ct * 2048 + off_h0); \
            const frag8 kf1 = *(const frag8*)(KsB + ((c) % 3) * 8192 + ct * 2048 + off_h1); \
            const hv4 vv = *(const hv4*)(vfix + (c) * 64 + ct * 16 + lg * 4);  \
            const hv4 av = vv * sel + one1;                                    \
            _Pragma("unroll")                                                  \
            for (int qt = 0; qt < 4; ++qt) {                                   \
                facc4 s_ = __builtin_amdgcn_mfma_f32_16x16x32_bf16(kf0, qf[qt][0], z4, 0, 0, 0); \
                s_ = __builtin_amdgcn_mfma_f32_16x16x32_bf16(kf1, qf[qt][1], s_, 0, 0, 0); \
                const hv2 p01 = __builtin_bit_cast(hv2,                        \
                    __builtin_amdgcn_cvt_pkrtz(__builtin_amdgcn_exp2f(s_[0]),  \
                                               __builtin_amdgcn_exp2f(s_[1]))); \
                const hv2 p23 = __builtin_bit_cast(hv2,                        \
                    __builtin_amdgcn_cvt_pkrtz(__builtin_amdgcn_exp2f(s_[2]),  \
                                               __builtin_amdgcn_exp2f(s_[3]))); \
                hv4 pb; pb[0] = p01[0]; pb[1] = p01[1]; pb[2] = p23[0]; pb[3] = p23[1]; \
                acc[qt] = __builtin_amdgcn_mfma_f32_16x16x16f16(av, pb, acc[qt], 0, 0, 0); \
            }                                                                  \
        }                                                                      \
    } while (0)

// vmcnt BEFORE barrier: each wave certifies its own chunk-c loads landed, the
// barrier then guarantees all waves' quarters are visible. Empty asm after the
// barrier = compiler fence so ds_reads aren't hoisted above it.
#define ITER_S(c, Nw) {                                                        \
        asm volatile("s_waitcnt vmcnt(" Nw ")" ::: "memory");                  \
        __builtin_amdgcn_s_barrier();                                          \
        asm volatile("" ::: "memory");                                         \
        STAGE((c) + 2);                                                        \
        CHUNK(c);                                                              \
    }
#define ITER_N(c, Nw) {                                                        \
        asm volatile("s_waitcnt vmcnt(" Nw ")" ::: "memory");                  \
        __builtin_amdgcn_s_barrier();                                          \
        asm volatile("" ::: "memory");                                         \
        CHUNK(c);                                                              \
    }

    STAGE(0);
    STAGE(1);
    ITER_S(0, "2") ITER_S(1, "2") ITER_S(2, "2") ITER_S(3, "2")
    ITER_S(4, "2") ITER_S(5, "2") ITER_N(6, "2") ITER_N(7, "0")

#undef STAGE
#undef CHUNK
#undef ITER_S
#undef ITER_N

    // num = acc[qt][0], den = acc[qt][1] in lanes lg==0 (C/D row = lg*4+r)
    if (lg == 0) {
#pragma unroll
        for (int qt = 0; qt < 4; ++qt) {
            const int row = q0 + qt * 16 + lr;
            float2 pr; pr.x = acc[qt][0]; pr.y = acc[qt][1];
            part[(size_t)split * (M_ * HEAD_) + ((size_t)(b * N_ + row)) * HEAD_ + h] = pr;
        }
    }
}

// ---------------- Kernel 4: combine split-KV partials --------------------
__global__ __launch_bounds__(256) void reduce_kernel(const float2* __restrict__ part,
                                                     const float* __restrict__ Ain,
                                                     float* __restrict__ outp) {
    const int i = blockIdx.x * 256 + threadIdx.x;   // 0..131071 == out layout
    const float2 p0 = part[i];
    const float2 p1 = part[1 * (M_ * HEAD_) + i];
    const float2 p2 = part[2 * (M_ * HEAD_) + i];
    const float2 p3 = part[3 * (M_ * HEAD_) + i];
    outp[i] = Ain[i] + (p0.x + p1.x + p2.x + p3.x) / (p0.y + p1.y + p2.y + p3.y);
}

// ---------------- launch ----------------
extern "C" void kernel_launch(void* const* d_in, const int* in_sizes, int n_in,
                              void* d_out, int out_size, void* d_ws, size_t ws_size,
                              hipStream_t stream) {
    const float* x   = (const float*)d_in[0];
    const float* A   = (const float*)d_in[1];
    const float* lw  = (const float*)d_in[2];
    const float* lb  = (const float*)d_in[3];
    const float* Wqk = (const float*)d_in[4];
    const float* wv  = (const float*)d_in[5];
    float* outp = (float*)d_out;

    char* ws = (char*)d_ws;
    unsigned short* xn  = (unsigned short*)(ws);                      // 16 MB (dead after gemm)
    unsigned short* wb  = (unsigned short*)(ws + 16u * 1024 * 1024);  //  4 MB
    unsigned short* qb  = (unsigned short*)(ws + 20u * 1024 * 1024);  // 16 MB
    unsigned short* kb  = (unsigned short*)(ws + 36u * 1024 * 1024);  // 16 MB
    unsigned short* v16 = (unsigned short*)(ws + 52u * 1024 * 1024);  // 256 KB
    float2*         part = (float2*)(ws);                             // 4 MB, reuses xn region

    ln_kernel<<<M_, 256, 0, stream>>>(x, lw, lb, xn);
    cvt_kernel<<<(E_ * DIM_ / 4) / 256, 256, 0, stream>>>(Wqk, wb);
    vprep_kernel<<<B_ * HEAD_, 256, 0, stream>>>(A, wv, v16);
    gemm_qk<<<64 * 16, 256, 0, stream>>>(xn, wb, qb, kb);
    attn_kernel<<<2048, 256, 0, stream>>>(qb, kb, v16, part);
    reduce_kernel<<<(M_ * HEAD_) / 256, 256, 0, stream>>>(part, A, outp);
}

// Round 9
// 117.151 us; speedup vs baseline: 1.0637x; 1.0637x over previous
//
#include <hip/hip_runtime.h>

// Problem constants (B=4, N=2048, DIM=1024, HEAD=16, HD=64)
#define B_    4
#define N_    2048
#define DIM_  1024
#define HEAD_ 16
#define HD_   64
#define M_    (B_*N_)    // 8192 rows
#define E_    (2*DIM_)   // 2048 projection outputs

typedef short          frag8 __attribute__((ext_vector_type(8)));  // 8 bf16 (4 VGPRs)
typedef float          facc4 __attribute__((ext_vector_type(4)));  // MFMA accum
typedef unsigned short ush4  __attribute__((ext_vector_type(4)));
typedef _Float16       hv4   __attribute__((ext_vector_type(4)));  // 4 f16 (2 VGPRs)
typedef _Float16       hv2   __attribute__((ext_vector_type(2)));

#define AS1 __attribute__((address_space(1)))
#define AS3 __attribute__((address_space(3)))

__device__ __forceinline__ void gld_lds16(const void* g, void* l) {
    // async global->LDS, 16B per lane; LDS dest = wave-uniform base + lane*16
    __builtin_amdgcn_global_load_lds((AS1 void*)(void*)g, (AS3 void*)l, 16, 0, 0);
}

__device__ __forceinline__ unsigned short f2bf(float f) {
    return __builtin_bit_cast(unsigned short, (__bf16)f);
}

// ---------------- Kernel 1: LayerNorm -> bf16 ----------------
__global__ __launch_bounds__(256) void ln_kernel(const float* __restrict__ x,
                                                 const float* __restrict__ lw,
                                                 const float* __restrict__ lb,
                                                 unsigned short* __restrict__ xn) {
    const int row = blockIdx.x;          // 0..8191
    const int t   = threadIdx.x;         // 256 threads, 4 elems each
    const float4 v = ((const float4*)(x + (size_t)row * DIM_))[t];
    float s  = v.x + v.y + v.z + v.w;
    float sq = v.x*v.x + v.y*v.y + v.z*v.z + v.w*v.w;
#pragma unroll
    for (int off = 32; off > 0; off >>= 1) {
        s  += __shfl_xor(s,  off);
        sq += __shfl_xor(sq, off);
    }
    __shared__ float red[8];
    const int w = t >> 6;
    if ((t & 63) == 0) { red[w] = s; red[4 + w] = sq; }
    __syncthreads();
    s  = red[0] + red[1] + red[2] + red[3];
    sq = red[4] + red[5] + red[6] + red[7];
    const float mu   = s * (1.0f / DIM_);
    const float rstd = rsqrtf(sq * (1.0f / DIM_) - mu * mu + 1e-5f);
    const float4 wv4 = ((const float4*)lw)[t];
    const float4 bv4 = ((const float4*)lb)[t];
    ush4 o;
    o[0] = f2bf((v.x - mu) * rstd * wv4.x + bv4.x);
    o[1] = f2bf((v.y - mu) * rstd * wv4.y + bv4.y);
    o[2] = f2bf((v.z - mu) * rstd * wv4.z + bv4.z);
    o[3] = f2bf((v.w - mu) * rstd * wv4.w + bv4.w);
    *(ush4*)(xn + (size_t)row * DIM_ + t * 4) = o;
}

// ---------------- Kernel 1b: Wqk f32 -> bf16 ----------------
__global__ __launch_bounds__(256) void cvt_kernel(const float* __restrict__ in,
                                                  unsigned short* __restrict__ outp) {
    const int i = blockIdx.x * 256 + threadIdx.x;   // 524288 float4 groups
    const float4 v = ((const float4*)in)[i];
    ush4 o;
    o[0] = f2bf(v.x); o[1] = f2bf(v.y); o[2] = f2bf(v.z); o[3] = f2bf(v.w);
    ((ush4*)outp)[i] = o;
}

// ---------------- Kernel 1c: v16[bh][n] = (f16)(A[b][n][h] * wv) ------------
__global__ __launch_bounds__(256) void vprep_kernel(const float* __restrict__ A,
                                                    const float* __restrict__ wv,
                                                    unsigned short* __restrict__ v16) {
    const int bh = blockIdx.x;           // 0..63
    const int b = bh >> 4, h = bh & 15;
    const float wvv = wv[0];
#pragma unroll
    for (int i = 0; i < 8; ++i) {
        const int n = i * 256 + threadIdx.x;
        const float f = A[((size_t)(b * N_ + n)) * HEAD_ + h] * wvv;
        v16[(size_t)bh * N_ + n] = __builtin_bit_cast(unsigned short, (_Float16)f);
    }
}

// ---------------- Kernel 2: qk = xn @ Wqk^T  (NT GEMM, bf16 MFMA) ----------------
// 128x128 tile, BK=64, 4 waves of 64x64. Both-sides XOR swizzle (verified).
// XCD swizzle v2 (r8 post-mortem): r7 gave each XCD 2 bn-panels but ALL bm ->
// 16 MB xn per XCD, can't fit 4 MB L2 -> FETCH 115 MB. Now each XCD owns an
// 8-row bm slice (2 MB xn) x all 16 bn (4 MB wb): working set ~ L2 capacity.
// Scale folded into q: 1/32 (dim^-0.5) * log2(e)  -> attn uses exp2 directly.
__global__ __launch_bounds__(256) void gemm_qk(const unsigned short* __restrict__ xn,
                                               const unsigned short* __restrict__ wb,
                                               unsigned short* __restrict__ qo,
                                               unsigned short* __restrict__ ko) {
    __shared__ __attribute__((aligned(16))) unsigned short As[128 * 64];
    __shared__ __attribute__((aligned(16))) unsigned short Bs[128 * 64];
    const int t    = threadIdx.x;
    const int lane = t & 63;
    const int w    = t >> 6;
    const int wr   = w & 1, wc = w >> 1;        // 2x2 wave grid, 64x64 each
    const int lr   = lane & 15, lg = lane >> 4; // frag row-lane / k-group
    const int bid  = blockIdx.x;
    const int xcd  = bid & 7;                   // dispatch round-robins XCDs
    const int l    = bid >> 3;                  // 0..127 within XCD
    const int bm   = xcd * 8 + (l & 7);         // 8-row bm slice per XCD
    const int bn   = l >> 3;                    // 0..15
    const int m0   = bm * 128, e0 = bn * 128;

    facc4 acc[4][4] = {};

    for (int k0 = 0; k0 < DIM_; k0 += 64) {
#pragma unroll
        for (int it = 0; it < 4; ++it) {
            const int seg = it * 256 + t;
            const int row = seg >> 3;
            const int ss  = (seg & 7) ^ (row & 7);         // pre-swizzled source
            unsigned short* dstA = (unsigned short*)As + (size_t)(it * 256 + (t & ~63)) * 8;
            unsigned short* dstB = (unsigned short*)Bs + (size_t)(it * 256 + (t & ~63)) * 8;
            gld_lds16(xn + (size_t)(m0 + row) * DIM_ + k0 + ss * 8, dstA);
            gld_lds16(wb + (size_t)(e0 + row) * DIM_ + k0 + ss * 8, dstB);
        }
        __syncthreads();

        frag8 af[4][2];
#pragma unroll
        for (int rt = 0; rt < 4; ++rt) {
            const int row = wr * 64 + rt * 16 + lr;
            const int sw  = (row & 7) << 4;
            af[rt][0] = *(const frag8*)((const char*)As + row * 128 + ((lg * 16) ^ sw));
            af[rt][1] = *(const frag8*)((const char*)As + row * 128 + ((64 + lg * 16) ^ sw));
        }
#pragma unroll
        for (int ct = 0; ct < 4; ++ct) {
            const int row = wc * 64 + ct * 16 + lr;
            const int sw  = (row & 7) << 4;
            const frag8 b0 = *(const frag8*)((const char*)Bs + row * 128 + ((lg * 16) ^ sw));
            const frag8 b1 = *(const frag8*)((const char*)Bs + row * 128 + ((64 + lg * 16) ^ sw));
#pragma unroll
            for (int rt = 0; rt < 4; ++rt) {
                acc[rt][ct] = __builtin_amdgcn_mfma_f32_16x16x32_bf16(af[rt][0], b0, acc[rt][ct], 0, 0, 0);
                acc[rt][ct] = __builtin_amdgcn_mfma_f32_16x16x32_bf16(af[rt][1], b1, acc[rt][ct], 0, 0, 0);
            }
        }
        __syncthreads();
    }

    // Epilogue: scatter to head-major q/k [bh][n][64]; fold scale*log2e into q.
    const float QSCALE = 0.03125f * 1.4426950408889634f;
#pragma unroll
    for (int rt = 0; rt < 4; ++rt) {
#pragma unroll
        for (int ct = 0; ct < 4; ++ct) {
            const int eg = e0 + wc * 64 + ct * 16 + lr;
#pragma unroll
            for (int r = 0; r < 4; ++r) {
                const int   mg = m0 + wr * 64 + rt * 16 + lg * 4 + r;  // C/D: row=(lane>>4)*4+reg
                const int   b  = mg >> 11;
                const int   n  = mg & (N_ - 1);
                const float val = acc[rt][ct][r];
                if (eg < DIM_) {
                    const int h = eg >> 6, d = eg & 63;
                    qo[((size_t)((b * HEAD_ + h) * N_ + n)) * HD_ + d] = f2bf(val * QSCALE);
                } else {
                    const int e2 = eg - DIM_;
                    const int h = e2 >> 6, d = e2 & 63;
                    ko[((size_t)((b * HEAD_ + h) * N_ + n)) * HD_ + d] = f2bf(val);
                }
            }
        }
    }
}

// ---------------- Kernel 3: attention partials (split-KV x4) ----------------
// 3-buffer counted-vmcnt pipeline (T3/T4): prologue stages chunks 0,1; each
// iter: s_waitcnt vmcnt(2) [own chunk-c loads landed, c+1 in flight] BEFORE
// raw s_barrier, then stage c+2, then compute c. Never drains vmcnt to 0
// mid-loop. T5: setprio(1) around the MFMA+exp cluster (stage-vs-compute
// role split exists per iter).
__global__ __launch_bounds__(256) void attn_kernel(const unsigned short* __restrict__ q,
                                                   const unsigned short* __restrict__ kmat,
                                                   const unsigned short* __restrict__ v16,
                                                   float2* __restrict__ part) {
    __shared__ __attribute__((aligned(16))) char KsB[3 * 8192];
    const int t    = threadIdx.x;
    const int lane = t & 63, w = t >> 6;        // 4 waves, 64 q-rows each
    const int lr   = lane & 15, lg = lane >> 4;
    const int id    = blockIdx.x;
    const int split = id >> 9;                  // 0..3 (KV quarter)
    const int bh    = (id >> 3) & 63;
    const int qblk  = id & 7;
    const int b     = bh >> 4, h = bh & 15;
    const int q0    = qblk * 256 + w * 64;

    // per-lane constants
    const int row0  = t >> 3;
    const int koff  = row0 * HD_ + (((t & 7) ^ (row0 & 7)) * 8);   // staging src (elems)
    const int wbase = (t & ~63) * 16;                              // staging LDS dst (bytes)
    const int sw    = (lr & 7) << 4;
    const int off_h0 = lr * 128 + ((lg * 16) ^ sw);                // ds_read vaddr (bytes)
    const int off_h1 = lr * 128 + ((64 + lg * 16) ^ sw);

    const unsigned short* qbase = q    + (size_t)bh * N_ * HD_;
    const unsigned short* kfix  = kmat + (size_t)bh * N_ * HD_ + (size_t)split * 512 * HD_;
    const unsigned short* vfix  = v16  + (size_t)bh * N_ + split * 512;

    // Q fragments in registers (B-operand: col=lr -> q-row, k = hh*32 + lg*8)
    frag8 qf[4][2];
#pragma unroll
    for (int qt = 0; qt < 4; ++qt) {
#pragma unroll
        for (int hh = 0; hh < 2; ++hh)
            qf[qt][hh] = *(const frag8*)(qbase + (size_t)(q0 + qt * 16 + lr) * HD_ + hh * 32 + lg * 8);
    }

    // PV A-operand masks: row0 -> v (num), row1 -> 1 (den)
    hv4 sel, one1;
#pragma unroll
    for (int j = 0; j < 4; ++j) {
        sel[j]  = (lr == 0) ? (_Float16)1.f : (_Float16)0.f;
        one1[j] = (lr == 1) ? (_Float16)1.f : (_Float16)0.f;
    }
    const facc4 z4 = {0.f, 0.f, 0.f, 0.f};
    facc4 acc[4] = {};

#define STAGE(c) do {                                                          \
        gld_lds16(kfix + (c) * 64 * HD_ + koff,                                \
                  KsB + ((c) % 3) * 8192 + wbase);                             \
        gld_lds16(kfix + (c) * 64 * HD_ + koff + 2048,                         \
                  KsB + ((c) % 3) * 8192 + 4096 + wbase);                      \
    } while (0)

#define CHUNK(c) do {                                                          \
        __builtin_amdgcn_s_setprio(1);                                         \
        _Pragma("unroll")                                                      \
        for (int ct = 0; ct < 4; ++ct) {                                       \
            const frag8 kf0 = *(const frag8*)(KsB + ((c) % 3) * 8192 + ct * 2048 + off_h0); \
            const frag8 kf1 = *(const frag8*)(KsB + ((c) % 3) * 8192 + ct * 2048 + off_h1); \
            const hv4 vv = *(const hv4*)(vfix + (c) * 64 + ct * 16 + lg * 4);  \
            const hv4 av = vv * sel + one1;                                    \
            _Pragma("unroll")                                                  \
            for (int qt = 0; qt < 4; ++qt) {                                   \
                facc4 s_ = __builtin_amdgcn_mfma_f32_16x16x32_bf16(kf0, qf[qt][0], z4, 0, 0, 0); \
                s_ = __builtin_amdgcn_mfma_f32_16x16x32_bf16(kf1, qf[qt][1], s_, 0, 0, 0); \
                const hv2 p01 = __builtin_bit_cast(hv2,                        \
                    __builtin_amdgcn_cvt_pkrtz(__builtin_amdgcn_exp2f(s_[0]),  \
                                               __builtin_amdgcn_exp2f(s_[1]))); \
                const hv2 p23 = __builtin_bit_cast(hv2,                        \
                    __builtin_amdgcn_cvt_pkrtz(__builtin_amdgcn_exp2f(s_[2]),  \
                                               __builtin_amdgcn_exp2f(s_[3]))); \
                hv4 pb; pb[0] = p01[0]; pb[1] = p01[1]; pb[2] = p23[0]; pb[3] = p23[1]; \
                acc[qt] = __builtin_amdgcn_mfma_f32_16x16x16f16(av, pb, acc[qt], 0, 0, 0); \
            }                                                                  \
        }                                                                      \
        __builtin_amdgcn_s_setprio(0);                                         \
    } while (0)

// vmcnt BEFORE barrier: each wave certifies its own chunk-c loads landed, the
// barrier then guarantees all waves' quarters are visible. Empty asm after the
// barrier = compiler fence so ds_reads aren't hoisted above it.
#define ITER_S(c, Nw) {                                                        \
        asm volatile("s_waitcnt vmcnt(" Nw ")" ::: "memory");                  \
        __builtin_amdgcn_s_barrier();                                          \
        asm volatile("" ::: "memory");                                         \
        STAGE((c) + 2);                                                        \
        CHUNK(c);                                                              \
    }
#define ITER_N(c, Nw) {                                                        \
        asm volatile("s_waitcnt vmcnt(" Nw ")" ::: "memory");                  \
        __builtin_amdgcn_s_barrier();                                          \
        asm volatile("" ::: "memory");                                         \
        CHUNK(c);                                                              \
    }

    STAGE(0);
    STAGE(1);
    ITER_S(0, "2") ITER_S(1, "2") ITER_S(2, "2") ITER_S(3, "2")
    ITER_S(4, "2") ITER_S(5, "2") ITER_N(6, "2") ITER_N(7, "0")

#undef STAGE
#undef CHUNK
#undef ITER_S
#undef ITER_N

    // num = acc[qt][0], den = acc[qt][1] in lanes lg==0 (C/D row = lg*4+r)
    if (lg == 0) {
#pragma unroll
        for (int qt = 0; qt < 4; ++qt) {
            const int row = q0 + qt * 16 + lr;
            float2 pr; pr.x = acc[qt][0]; pr.y = acc[qt][1];
            part[(size_t)split * (M_ * HEAD_) + ((size_t)(b * N_ + row)) * HEAD_ + h] = pr;
        }
    }
}

// ---------------- Kernel 4: combine split-KV partials --------------------
__global__ __launch_bounds__(256) void reduce_kernel(const float2* __restrict__ part,
                                                     const float* __restrict__ Ain,
                                                     float* __restrict__ outp) {
    const int i = blockIdx.x * 256 + threadIdx.x;   // 0..131071 == out layout
    const float2 p0 = part[i];
    const float2 p1 = part[1 * (M_ * HEAD_) + i];
    const float2 p2 = part[2 * (M_ * HEAD_) + i];
    const float2 p3 = part[3 * (M_ * HEAD_) + i];
    outp[i] = Ain[i] + (p0.x + p1.x + p2.x + p3.x) / (p0.y + p1.y + p2.y + p3.y);
}

// ---------------- launch ----------------
extern "C" void kernel_launch(void* const* d_in, const int* in_sizes, int n_in,
                              void* d_out, int out_size, void* d_ws, size_t ws_size,
                              hipStream_t stream) {
    const float* x   = (const float*)d_in[0];
    const float* A   = (const float*)d_in[1];
    const float* lw  = (const float*)d_in[2];
    const float* lb  = (const float*)d_in[3];
    const float* Wqk = (const float*)d_in[4];
    const float* wv  = (const float*)d_in[5];
    float* outp = (float*)d_out;

    char* ws = (char*)d_ws;
    unsigned short* xn  = (unsigned short*)(ws);                      // 16 MB (dead after gemm)
    unsigned short* wb  = (unsigned short*)(ws + 16u * 1024 * 1024);  //  4 MB
    unsigned short* qb  = (unsigned short*)(ws + 20u * 1024 * 1024);  // 16 MB
    unsigned short* kb  = (unsigned short*)(ws + 36u * 1024 * 1024);  // 16 MB
    unsigned short* v16 = (unsigned short*)(ws + 52u * 1024 * 1024);  // 256 KB
    float2*         part = (float2*)(ws);                             // 4 MB, reuses xn region

    ln_kernel<<<M_, 256, 0, stream>>>(x, lw, lb, xn);
    cvt_kernel<<<(E_ * DIM_ / 4) / 256, 256, 0, stream>>>(Wqk, wb);
    vprep_kernel<<<B_ * HEAD_, 256, 0, stream>>>(A, wv, v16);
    gemm_qk<<<64 * 16, 256, 0, stream>>>(xn, wb, qb, kb);
    attn_kernel<<<2048, 256, 0, stream>>>(qb, kb, v16, part);
    reduce_kernel<<<(M_ * HEAD_) / 256, 256, 0, stream>>>(part, A, outp);
}

// Round 10
// 103.033 us; speedup vs baseline: 1.2094x; 1.1370x over previous
//
#include <hip/hip_runtime.h>

// Problem constants (B=4, N=2048, DIM=1024, HEAD=16, HD=64)
#define B_    4
#define N_    2048
#define DIM_  1024
#define HEAD_ 16
#define HD_   64
#define M_    (B_*N_)    // 8192 rows
#define E_    (2*DIM_)   // 2048 projection outputs

typedef short          frag8 __attribute__((ext_vector_type(8)));  // 8 bf16 (4 VGPRs)
typedef float          facc4 __attribute__((ext_vector_type(4)));  // MFMA accum
typedef unsigned short ush4  __attribute__((ext_vector_type(4)));
typedef _Float16       hv4   __attribute__((ext_vector_type(4)));  // 4 f16 (2 VGPRs)
typedef _Float16       hv2   __attribute__((ext_vector_type(2)));

#define AS1 __attribute__((address_space(1)))
#define AS3 __attribute__((address_space(3)))

__device__ __forceinline__ void gld_lds16(const void* g, void* l) {
    // async global->LDS, 16B per lane; LDS dest = wave-uniform base + lane*16
    __builtin_amdgcn_global_load_lds((AS1 void*)(void*)g, (AS3 void*)l, 16, 0, 0);
}

__device__ __forceinline__ unsigned short f2bf(float f) {
    return __builtin_bit_cast(unsigned short, (__bf16)f);
}

// ---------------- Kernel 1: fused prep (LN -> bf16 | Wqk cvt | vprep) -------
__global__ __launch_bounds__(256) void prep_kernel(const float* __restrict__ x,
                                                   const float* __restrict__ lw,
                                                   const float* __restrict__ lb,
                                                   const float* __restrict__ Wqk,
                                                   const float* __restrict__ A,
                                                   const float* __restrict__ wv,
                                                   unsigned short* __restrict__ xn,
                                                   unsigned short* __restrict__ wb,
                                                   unsigned short* __restrict__ v16) {
    __shared__ float red[8];
    const int bid = blockIdx.x;
    const int t   = threadIdx.x;
    if (bid < M_) {
        // LayerNorm row
        const float4 v = ((const float4*)(x + (size_t)bid * DIM_))[t];
        float s  = v.x + v.y + v.z + v.w;
        float sq = v.x*v.x + v.y*v.y + v.z*v.z + v.w*v.w;
#pragma unroll
        for (int off = 32; off > 0; off >>= 1) {
            s  += __shfl_xor(s,  off);
            sq += __shfl_xor(sq, off);
        }
        const int w = t >> 6;
        if ((t & 63) == 0) { red[w] = s; red[4 + w] = sq; }
        __syncthreads();
        s  = red[0] + red[1] + red[2] + red[3];
        sq = red[4] + red[5] + red[6] + red[7];
        const float mu   = s * (1.0f / DIM_);
        const float rstd = rsqrtf(sq * (1.0f / DIM_) - mu * mu + 1e-5f);
        const float4 wv4 = ((const float4*)lw)[t];
        const float4 bv4 = ((const float4*)lb)[t];
        ush4 o;
        o[0] = f2bf((v.x - mu) * rstd * wv4.x + bv4.x);
        o[1] = f2bf((v.y - mu) * rstd * wv4.y + bv4.y);
        o[2] = f2bf((v.z - mu) * rstd * wv4.z + bv4.z);
        o[3] = f2bf((v.w - mu) * rstd * wv4.w + bv4.w);
        *(ush4*)(xn + (size_t)bid * DIM_ + t * 4) = o;
    } else if (bid < M_ + 2048) {
        // Wqk f32 -> bf16 (524288 float4 groups)
        const int i = (bid - M_) * 256 + t;
        const float4 v = ((const float4*)Wqk)[i];
        ush4 o;
        o[0] = f2bf(v.x); o[1] = f2bf(v.y); o[2] = f2bf(v.z); o[3] = f2bf(v.w);
        ((ush4*)wb)[i] = o;
    } else {
        // v16[bh][n] = (f16)(A[b][n][h] * wv)
        const int bh = bid - (M_ + 2048);
        const int b = bh >> 4, h = bh & 15;
        const float wvv = wv[0];
#pragma unroll
        for (int i = 0; i < 8; ++i) {
            const int n = i * 256 + t;
            const float f = A[((size_t)(b * N_ + n)) * HEAD_ + h] * wvv;
            v16[(size_t)bh * N_ + n] = __builtin_bit_cast(unsigned short, (_Float16)f);
        }
    }
}

// ---------------- Kernel 2: qk = xn @ Wqk^T  (256x256 deep-pipelined) -------
// 256x256 tile, BK=64, 8 waves (512 thr, wr=wid>>2, wc=wid&3), per-wave out
// 128x64 (acc[8][4]). LDS 128 KB: 2 buffers x (A 32 KB + B 32 KB), row
// stride 128 B, both-sides XOR swizzle (verified scheme). 4 phases per K-tile
// (quadrants (mh,nh) in order 00,01,10,11; A-half held in regs across nh).
// Counted pipeline: each phase = { vmcnt(8); s_barrier; ds-reads; stage one
// designated half-tile; lgkmcnt(0); 16 MFMA }. Stage targets the slot freed
// exactly one barrier earlier (safety by ordering); vmcnt(8) forces stages
// >=5 phases old to have landed (per-phase issue counts 2,2,0,4 sum to 8 over
// any 4-phase window). Never drains vmcnt mid-loop (T3/T4). Tail (m=15) uses
// gates 2,0,-,-. XCD mapping: bm=bid&31 -> xcd=bm%8 owns 4 A-panels (2 MB,
// L2-resident) x all 8 bn. Scale*log2e folded into q.
__global__ __launch_bounds__(512, 2) void gemm_qk(const unsigned short* __restrict__ xn,
                                                  const unsigned short* __restrict__ wb,
                                                  unsigned short* __restrict__ qo,
                                                  unsigned short* __restrict__ ko) {
    __shared__ __attribute__((aligned(16))) char lds[131072];
    const int t    = threadIdx.x;             // 0..511
    const int lane = t & 63;
    const int wid  = t >> 6;                  // 0..7
    const int wr   = wid >> 2, wc = wid & 3;  // 2x4 wave grid, 128x64 each
    const int lr   = lane & 15, lg = lane >> 4;
    const int bid  = blockIdx.x;
    const int bm   = bid & 31, bn = bid >> 5;
    const int m0   = bm * 256, e0 = bn * 256;

    // staging constants
    const int srow = t >> 3;                  // 0..63
    const int ss8  = ((t & 7) ^ (srow & 7)) * 8;
    const int wu16 = (t & ~63) * 16;

    facc4 acc[8][4] = {};
    frag8 a[4][2], b[2][2];

// stage half-tile `half` (0=rows 0-127,1=128-255) of matrix `mat` (0=A,1=B),
// K-tile `tile`, into buf[tile&1]; 2 gld_lds16 per thread (16 KB total).
#define STG(mat, tile, half) do {                                              \
        const unsigned short* sp_ = (mat) ? wb : xn;                           \
        const int rb_ = (mat) ? e0 : m0;                                       \
        _Pragma("unroll")                                                      \
        for (int l_ = 0; l_ < 2; ++l_)                                         \
            gld_lds16(sp_ + (size_t)(rb_ + (half)*128 + l_*64 + srow) * DIM_   \
                          + (tile)*64 + ss8,                                   \
                      lds + ((tile)&1)*65536 + (mat)*32768 + (half)*16384      \
                          + l_*8192 + wu16);                                   \
    } while (0)

#define LDA(mh) do {                                                           \
        _Pragma("unroll")                                                      \
        for (int mf_ = 0; mf_ < 4; ++mf_) {                                    \
            const int row_ = wr*128 + (mh)*64 + mf_*16 + lr;                   \
            const int sw_  = (row_ & 7) << 4;                                  \
            const char* ab_ = lds + cb*65536;                                  \
            a[mf_][0] = *(const frag8*)(ab_ + row_*128 + ((lg*16) ^ sw_));     \
            a[mf_][1] = *(const frag8*)(ab_ + row_*128 + ((64 + lg*16) ^ sw_));\
        }                                                                      \
    } while (0)

#define LDB(nh) do {                                                           \
        _Pragma("unroll")                                                      \
        for (int nf_ = 0; nf_ < 2; ++nf_) {                                    \
            const int row_ = wc*64 + (nh)*32 + nf_*16 + lr;                    \
            const int sw_  = (row_ & 7) << 4;                                  \
            const char* bb_ = lds + cb*65536 + 32768;                          \
            b[nf_][0] = *(const frag8*)(bb_ + row_*128 + ((lg*16) ^ sw_));     \
            b[nf_][1] = *(const frag8*)(bb_ + row_*128 + ((64 + lg*16) ^ sw_));\
        }                                                                      \
    } while (0)

#define MM(mh, nh) do {                                                        \
        __builtin_amdgcn_s_setprio(1);                                         \
        _Pragma("unroll")                                                      \
        for (int mf_ = 0; mf_ < 4; ++mf_)                                      \
        _Pragma("unroll")                                                      \
        for (int nf_ = 0; nf_ < 2; ++nf_) {                                    \
            acc[(mh)*4+mf_][(nh)*2+nf_] = __builtin_amdgcn_mfma_f32_16x16x32_bf16( \
                a[mf_][0], b[nf_][0], acc[(mh)*4+mf_][(nh)*2+nf_], 0, 0, 0);   \
            acc[(mh)*4+mf_][(nh)*2+nf_] = __builtin_amdgcn_mfma_f32_16x16x32_bf16( \
                a[mf_][1], b[nf_][1], acc[(mh)*4+mf_][(nh)*2+nf_], 0, 0, 0);   \
        }                                                                      \
        __builtin_amdgcn_s_setprio(0);                                         \
    } while (0)

#define PH_SYNC(NW) do {                                                       \
        asm volatile("s_waitcnt vmcnt(" NW ")" ::: "memory");                  \
        __builtin_amdgcn_s_barrier();                                          \
        asm volatile("" ::: "memory");                                         \
    } while (0)
#define PH_BAR() do {                                                          \
        __builtin_amdgcn_s_barrier();                                          \
        asm volatile("" ::: "memory");                                         \
    } while (0)
#define PH_LGKM() do {                                                         \
        asm volatile("s_waitcnt lgkmcnt(0)" ::: "memory");                     \
        __builtin_amdgcn_sched_barrier(0);                                     \
    } while (0)

    // Prologue: K0 fully + A-lo1, A-hi1, B-lo1 (14 loads; B-hi1 staged at m=0,i0)
    STG(0, 0, 0);  STG(1, 0, 0);  STG(0, 0, 1);  STG(1, 0, 1);
    STG(0, 1, 0);  STG(0, 1, 1);  STG(1, 1, 0);

    for (int m = 0; m < 15; ++m) {
        const int cb = m & 1;
        // phase i=0: quadrant (0,0); stage B-hi(m+1)
        PH_SYNC("8");
        LDA(0); LDB(0);
        STG(1, m + 1, 1);
        PH_LGKM();
        MM(0, 0);
        // phase i=1: quadrant (0,1); stage A-lo(m+2)
        PH_SYNC("8");
        LDB(1);
        if (m <= 13) STG(0, m + 2, 0);
        PH_LGKM();
        MM(0, 1);
        // phase i=2: quadrant (1,0)
        PH_SYNC("8");
        LDA(1); LDB(0);
        PH_LGKM();
        MM(1, 0);
        // phase i=3: quadrant (1,1); stage A-hi(m+2), B-lo(m+2)
        PH_SYNC("8");
        LDB(1);
        if (m <= 13) { STG(0, m + 2, 1); STG(1, m + 2, 0); }
        PH_LGKM();
        MM(1, 1);
    }
    // m = 15 tail: no stages; gates force the last half-tiles
    {
        const int cb = 1;
        PH_SYNC("2");  LDA(0); LDB(0); PH_LGKM(); MM(0, 0);
        PH_SYNC("0");  LDB(1);         PH_LGKM(); MM(0, 1);
        PH_BAR();      LDA(1); LDB(0); PH_LGKM(); MM(1, 0);
        PH_BAR();      LDB(1);         PH_LGKM(); MM(1, 1);
    }
#undef STG
#undef LDA
#undef LDB
#undef MM
#undef PH_SYNC
#undef PH_BAR
#undef PH_LGKM

    // Epilogue: scatter to head-major q/k [bh][n][64]; fold scale*log2e into q.
    const float QSCALE = 0.03125f * 1.4426950408889634f;
#pragma unroll
    for (int mf8 = 0; mf8 < 8; ++mf8) {
#pragma unroll
        for (int nf4 = 0; nf4 < 4; ++nf4) {
            const int eg = e0 + wc * 64 + nf4 * 16 + lr;
#pragma unroll
            for (int r = 0; r < 4; ++r) {
                const int   mg = m0 + wr * 128 + mf8 * 16 + lg * 4 + r;
                const int   b_  = mg >> 11;
                const int   n  = mg & (N_ - 1);
                const float val = acc[mf8][nf4][r];
                if (eg < DIM_) {
                    const int h = eg >> 6, d = eg & 63;
                    qo[((size_t)((b_ * HEAD_ + h) * N_ + n)) * HD_ + d] = f2bf(val * QSCALE);
                } else {
                    const int e2 = eg - DIM_;
                    const int h = e2 >> 6, d = e2 & 63;
                    ko[((size_t)((b_ * HEAD_ + h) * N_ + n)) * HD_ + d] = f2bf(val);
                }
            }
        }
    }
}

// ---------------- Kernel 3: attention partials (split-KV x4) ----------------
// 3-buffer counted-vmcnt pipeline (unchanged from r9; ~55 us plateau).
__global__ __launch_bounds__(256) void attn_kernel(const unsigned short* __restrict__ q,
                                                   const unsigned short* __restrict__ kmat,
                                                   const unsigned short* __restrict__ v16,
                                                   float2* __restrict__ part) {
    __shared__ __attribute__((aligned(16))) char KsB[3 * 8192];
    const int t    = threadIdx.x;
    const int lane = t & 63, w = t >> 6;        // 4 waves, 64 q-rows each
    const int lr   = lane & 15, lg = lane >> 4;
    const int id    = blockIdx.x;
    const int split = id >> 9;                  // 0..3 (KV quarter)
    const int bh    = (id >> 3) & 63;
    const int qblk  = id & 7;
    const int b     = bh >> 4, h = bh & 15;
    const int q0    = qblk * 256 + w * 64;

    const int row0  = t >> 3;
    const int koff  = row0 * HD_ + (((t & 7) ^ (row0 & 7)) * 8);
    const int wbase = (t & ~63) * 16;
    const int sw    = (lr & 7) << 4;
    const int off_h0 = lr * 128 + ((lg * 16) ^ sw);
    const int off_h1 = lr * 128 + ((64 + lg * 16) ^ sw);

    const unsigned short* qbase = q    + (size_t)bh * N_ * HD_;
    const unsigned short* kfix  = kmat + (size_t)bh * N_ * HD_ + (size_t)split * 512 * HD_;
    const unsigned short* vfix  = v16  + (size_t)bh * N_ + split * 512;

    frag8 qf[4][2];
#pragma unroll
    for (int qt = 0; qt < 4; ++qt) {
#pragma unroll
        for (int hh = 0; hh < 2; ++hh)
            qf[qt][hh] = *(const frag8*)(qbase + (size_t)(q0 + qt * 16 + lr) * HD_ + hh * 32 + lg * 8);
    }

    hv4 sel, one1;
#pragma unroll
    for (int j = 0; j < 4; ++j) {
        sel[j]  = (lr == 0) ? (_Float16)1.f : (_Float16)0.f;
        one1[j] = (lr == 1) ? (_Float16)1.f : (_Float16)0.f;
    }
    const facc4 z4 = {0.f, 0.f, 0.f, 0.f};
    facc4 acc[4] = {};

#define STAGE(c) do {                                                          \
        gld_lds16(kfix + (c) * 64 * HD_ + koff,                                \
                  KsB + ((c) % 3) * 8192 + wbase);                             \
        gld_lds16(kfix + (c) * 64 * HD_ + koff + 2048,                         \
                  KsB + ((c) % 3) * 8192 + 4096 + wbase);                      \
    } while (0)

#define CHUNK(c) do {                                                          \
        __builtin_amdgcn_s_setprio(1);                                         \
        _Pragma("unroll")                                                      \
        for (int ct = 0; ct < 4; ++ct) {                                       \
            const frag8 kf0 = *(const frag8*)(KsB + ((c) % 3) * 8192 + ct * 2048 + off_h0); \
            const frag8 kf1 = *(const frag8*)(KsB + ((c) % 3) * 8192 + ct * 2048 + off_h1); \
            const hv4 vv = *(const hv4*)(vfix + (c) * 64 + ct * 16 + lg * 4);  \
            const hv4 av = vv * sel + one1;                                    \
            _Pragma("unroll")                                                  \
            for (int qt = 0; qt < 4; ++qt) {                                   \
                facc4 s_ = __builtin_amdgcn_mfma_f32_16x16x32_bf16(kf0, qf[qt][0], z4, 0, 0, 0); \
                s_ = __builtin_amdgcn_mfma_f32_16x16x32_bf16(kf1, qf[qt][1], s_, 0, 0, 0); \
                const hv2 p01 = __builtin_bit_cast(hv2,                        \
                    __builtin_amdgcn_cvt_pkrtz(__builtin_amdgcn_exp2f(s_[0]),  \
                                               __builtin_amdgcn_exp2f(s_[1]))); \
                const hv2 p23 = __builtin_bit_cast(hv2,                        \
                    __builtin_amdgcn_cvt_pkrtz(__builtin_amdgcn_exp2f(s_[2]),  \
                                               __builtin_amdgcn_exp2f(s_[3]))); \
                hv4 pb; pb[0] = p01[0]; pb[1] = p01[1]; pb[2] = p23[0]; pb[3] = p23[1]; \
                acc[qt] = __builtin_amdgcn_mfma_f32_16x16x16f16(av, pb, acc[qt], 0, 0, 0); \
            }                                                                  \
        }                                                                      \
        __builtin_amdgcn_s_setprio(0);                                         \
    } while (0)

#define ITER_S(c, Nw) {                                                        \
        asm volatile("s_waitcnt vmcnt(" Nw ")" ::: "memory");                  \
        __builtin_amdgcn_s_barrier();                                          \
        asm volatile("" ::: "memory");                                         \
        STAGE((c) + 2);                                                        \
        CHUNK(c);                                                              \
    }
#define ITER_N(c, Nw) {                                                        \
        asm volatile("s_waitcnt vmcnt(" Nw ")" ::: "memory");                  \
        __builtin_amdgcn_s_barrier();                                          \
        asm volatile("" ::: "memory");                                         \
        CHUNK(c);                                                              \
    }

    STAGE(0);
    STAGE(1);
    ITER_S(0, "2") ITER_S(1, "2") ITER_S(2, "2") ITER_S(3, "2")
    ITER_S(4, "2") ITER_S(5, "2") ITER_N(6, "2") ITER_N(7, "0")

#undef STAGE
#undef CHUNK
#undef ITER_S
#undef ITER_N

    if (lg == 0) {
#pragma unroll
        for (int qt = 0; qt < 4; ++qt) {
            const int row = q0 + qt * 16 + lr;
            float2 pr; pr.x = acc[qt][0]; pr.y = acc[qt][1];
            part[(size_t)split * (M_ * HEAD_) + ((size_t)(b * N_ + row)) * HEAD_ + h] = pr;
        }
    }
}

// ---------------- Kernel 4: combine split-KV partials --------------------
__global__ __launch_bounds__(256) void reduce_kernel(const float2* __restrict__ part,
                                                     const float* __restrict__ Ain,
                                                     float* __restrict__ outp) {
    const int i = blockIdx.x * 256 + threadIdx.x;   // 0..131071 == out layout
    const float2 p0 = part[i];
    const float2 p1 = part[1 * (M_ * HEAD_) + i];
    const float2 p2 = part[2 * (M_ * HEAD_) + i];
    const float2 p3 = part[3 * (M_ * HEAD_) + i];
    outp[i] = Ain[i] + (p0.x + p1.x + p2.x + p3.x) / (p0.y + p1.y + p2.y + p3.y);
}

// ---------------- launch ----------------
extern "C" void kernel_launch(void* const* d_in, const int* in_sizes, int n_in,
                              void* d_out, int out_size, void* d_ws, size_t ws_size,
                              hipStream_t stream) {
    const float* x   = (const float*)d_in[0];
    const float* A   = (const float*)d_in[1];
    const float* lw  = (const float*)d_in[2];
    const float* lb  = (const float*)d_in[3];
    const float* Wqk = (const float*)d_in[4];
    const float* wv  = (const float*)d_in[5];
    float* outp = (float*)d_out;

    char* ws = (char*)d_ws;
    unsigned short* xn  = (unsigned short*)(ws);                      // 16 MB (dead after gemm)
    unsigned short* wb  = (unsigned short*)(ws + 16u * 1024 * 1024);  //  4 MB
    unsigned short* qb  = (unsigned short*)(ws + 20u * 1024 * 1024);  // 16 MB
    unsigned short* kb  = (unsigned short*)(ws + 36u * 1024 * 1024);  // 16 MB
    unsigned short* v16 = (unsigned short*)(ws + 52u * 1024 * 1024);  // 256 KB
    float2*         part = (float2*)(ws);                             // 4 MB, reuses xn region

    prep_kernel<<<M_ + 2048 + B_ * HEAD_, 256, 0, stream>>>(x, lw, lb, Wqk, A, wv, xn, wb, v16);
    gemm_qk<<<256, 512, 0, stream>>>(xn, wb, qb, kb);
    attn_kernel<<<2048, 256, 0, stream>>>(qb, kb, v16, part);
    reduce_kernel<<<(M_ * HEAD_) / 256, 256, 0, stream>>>(part, A, outp);
}